// Round 6
// baseline (961.672 us; speedup 1.0000x reference)
//
#include <hip/hip_runtime.h>
#include <math.h>

constexpr int B = 2, H = 320, W = 512, D = 64;
constexpr int HW = H * W;
constexpr int R = 10;            // BLOCK // 2
constexpr int SEG = 80;          // output rows per cost block
constexpr int NSEG = H / SEG;    // 4
constexpr int RS = 548;          // vsbuf row stride (words)
constexpr float EPS = 1e-12f;

// Normalize + pack into float4 planes: nrm4[((t*B+b)*2+side)*HW + hw] = (c0,c1,c2,0)
__global__ void k_norm(const float* __restrict__ x, const float* __restrict__ gt,
                       float4* __restrict__ nrm4) {
    int idx = blockIdx.x * blockDim.x + threadIdx.x;
    if (idx >= 2 * B * HW) return;
    int t = idx / (B * HW);
    int rem = idx - t * (B * HW);
    int b = rem / HW;
    int hw = rem - b * HW;
    const float* p = (t == 0 ? x : gt) + (size_t)b * 6 * HW + hw;
    float v0 = p[0],      v1 = p[HW],     v2 = p[2 * HW];
    float v3 = p[3 * HW], v4 = p[4 * HW], v5 = p[5 * HW];
    float n1 = fmaxf(sqrtf(v0 * v0 + v1 * v1 + v2 * v2), EPS);
    float n2 = fmaxf(sqrtf(v3 * v3 + v4 * v4 + v5 * v5), EPS);
    float4* q = nrm4 + (size_t)(t * B + b) * 2 * HW + hw;
    q[0]  = make_float4(v0 / n1, v1 / n1, v2 / n1, 0.f);
    q[HW] = make_float4(v3 / n2, v4 / n2, v5 / n2, 0.f);
}

// Fully-rolling 21x21 box-filtered SAD cost + fused argmin via packed atomicMin.
// Phase 1 (8-row superstep): hoisted ring reads -> 16 indep global loads ->
// ring writes -> vs chain -> vsbuf snapshots -> ONE barrier.
// Phase 2: 28-word window (7x ds_read_b128) -> 8 horizontal-rolled costs ->
// pack (costbits & ~63)|d -> pre-read filter -> no-return atomicMin.
// Ties (bitwise-equal costs across d) collapse to equal masked keys, so the
// |d low bits make the LOWEST d win == jnp.argmin semantics.
__global__ __launch_bounds__(512, 2) void k_cost(const float4* __restrict__ nrm4,
                                                 unsigned* __restrict__ keys, int t) {
    int blk = blockIdx.x;
    int combo = blk & 7;           // B*NSEG = 8 combos; pins combo to one XCD
    int d = blk >> 3;
    int b = combo >> 2;
    int seg = combo & 3;
    int w = threadIdx.x;           // phase-1 column
    const float4* L4 = nrm4 + (size_t)(t * B + b) * 2 * HW;
    const float4* R4 = L4 + HW;
    const bool val = (w >= d);
    const int wr = val ? (w - d) : 0;
    const int h0 = seg * SEG;

    __shared__ float ring[21][W];     // diff delay line, strictly per-column
    __shared__ float vsb[2][8][RS];   // double-buffered vs snapshots (+10 halo each side)

    {   // zero halo pads of both parity buffers once
        int j = w >> 6, k = w & 63;
        if (k < 10)      { vsb[0][j][k] = 0.f;       vsb[1][j][k] = 0.f; }
        else if (k < 20) { vsb[0][j][512 + k] = 0.f; vsb[1][j][512 + k] = 0.f; }
    }

    auto diff = [&](int h) -> float {
        float4 l = L4[(size_t)h * W + w];
        if (val) {
            float4 r = R4[(size_t)h * W + wr];
            return fabsf(l.x - r.x) + fabsf(l.y - r.y) + fabsf(l.z - r.z);
        }
        return fabsf(l.x) + fabsf(l.y) + fabsf(l.z);  // r_shift == 0 when invalid
    };

    // Warm-up: rows [h0-10, h0+9] -> ring slots 0..19; slot 20 = row h0-11 (zero).
    float vs = 0.f;
    for (int k = 0; k < 20; ++k) {
        int h = h0 - R + k;
        float dv0 = (h >= 0) ? diff(h) : 0.f;
        ring[k][w] = dv0;
        vs += dv0;
    }
    ring[20][w] = 0.f;

    const int cc = threadIdx.x >> 3;   // phase-2 col-run (0..63)
    const int jj = threadIdx.x & 7;    // phase-2 row slot (0..7)

    int slot0 = 20;                    // ring slot for first row of superstep
    for (int ss = 0; ss < SEG / 8; ++ss) {
        int sl[8];
        float dold[8], dv[8];
#pragma unroll
        for (int j = 0; j < 8; ++j) { int s2 = slot0 + j; if (s2 >= 21) s2 -= 21; sl[j] = s2; }
#pragma unroll
        for (int j = 0; j < 8; ++j) dold[j] = ring[sl[j]][w];     // 8 indep LDS reads
#pragma unroll
        for (int j = 0; j < 8; ++j) {                             // 16 indep global loads
            int hn = h0 + ss * 8 + j + R;
            dv[j] = (hn < H) ? diff(hn) : 0.f;
        }
#pragma unroll
        for (int j = 0; j < 8; ++j) ring[sl[j]][w] = dv[j];       // writes after all reads
        float* vrow = &vsb[ss & 1][0][0];
#pragma unroll
        for (int j = 0; j < 8; ++j) { vs += dv[j] - dold[j]; vrow[j * RS + 10 + w] = vs; }
        __syncthreads();
        // phase 2: 28-float window -> 8 outputs
        const float* vp = &vsb[ss & 1][jj][8 * cc];
        float wnd[28];
#pragma unroll
        for (int q = 0; q < 7; ++q) {
            float4 v4 = *(const float4*)(vp + 4 * q);
            wnd[4 * q] = v4.x; wnd[4 * q + 1] = v4.y;
            wnd[4 * q + 2] = v4.z; wnd[4 * q + 3] = v4.w;
        }
        float o = 0.f;
#pragma unroll
        for (int k = 0; k < 21; ++k) o += wnd[k];
        float out[8];
        out[0] = o;
#pragma unroll
        for (int k = 1; k < 8; ++k) { o += wnd[20 + k] - wnd[k - 1]; out[k] = o; }

        // fused argmin epilogue: pre-read filter + no-return atomicMin
        int hout = h0 + ss * 8 + jj;
        unsigned* kb = keys + (size_t)(b * H + hout) * W + 8 * cc;
        uint4 c0 = *(const uint4*)kb;
        uint4 c1 = *(const uint4*)(kb + 4);
        unsigned cur[8] = {c0.x, c0.y, c0.z, c0.w, c1.x, c1.y, c1.z, c1.w};
#pragma unroll
        for (int k = 0; k < 8; ++k) {
            unsigned key = (__float_as_uint(out[k]) & 0xFFFFFFC0u) | (unsigned)d;
            if (key < cur[k]) atomicMin(kb + k, key);
        }
        slot0 += 8; if (slot0 >= 21) slot0 -= 21;
    }
}

// |d1 - d0| + per-block partial sums (deterministic).
__global__ void k_final(const unsigned* __restrict__ k0, const unsigned* __restrict__ k1,
                        float* __restrict__ part) {
    int idx = blockIdx.x * 256 + threadIdx.x;
    float s = 0.f;
    if (idx < B * HW)
        s = fabsf((float)(int)(k0[idx] & 63u) - (float)(int)(k1[idx] & 63u));
    __shared__ float sm[256];
    sm[threadIdx.x] = s;
    __syncthreads();
    for (int off = 128; off; off >>= 1) {
        if (threadIdx.x < off) sm[threadIdx.x] += sm[threadIdx.x + off];
        __syncthreads();
    }
    if (!threadIdx.x) part[blockIdx.x] = sm[0];
}

__global__ void k_red2(const float* __restrict__ part, float* __restrict__ out,
                       int nb, float inv) {
    __shared__ float sm[256];
    int tid = threadIdx.x;
    float s = 0.f;
    for (int i = tid; i < nb; i += 256) s += part[i];
    sm[tid] = s;
    __syncthreads();
    for (int off = 128; off; off >>= 1) {
        if (tid < off) sm[tid] += sm[tid + off];
        __syncthreads();
    }
    if (!tid) out[0] = sm[0] * inv;
}

extern "C" void kernel_launch(void* const* d_in, const int* in_sizes, int n_in,
                              void* d_out, int out_size, void* d_ws, size_t ws_size,
                              hipStream_t stream) {
    const float* x  = (const float*)d_in[0];
    const float* gt = (const float*)d_in[1];

    float4* nrm4   = (float4*)d_ws;                           // 2*B*2*HW f4 = 21.0 MB
    unsigned* key0 = (unsigned*)(nrm4 + (size_t)2 * B * 2 * HW); // B*HW u32 = 1.3 MB
    unsigned* key1 = key0 + (size_t)B * HW;                      // B*HW u32 = 1.3 MB
    float* part    = (float*)(key1 + (size_t)B * HW);            // 1280 f32

    constexpr int NPIX_BLKS = (B * HW + 255) / 256;           // 1280

    hipMemsetAsync(key0, 0xFF, (size_t)2 * B * HW * sizeof(unsigned), stream);

    k_norm<<<(2 * B * HW + 255) / 256, 256, 0, stream>>>(x, gt, nrm4);
    k_cost<<<B * NSEG * D, 512, 0, stream>>>(nrm4, key0, 0);
    k_cost<<<B * NSEG * D, 512, 0, stream>>>(nrm4, key1, 1);

    k_final<<<NPIX_BLKS, 256, 0, stream>>>(key0, key1, part);
    k_red2<<<1, 256, 0, stream>>>(part, (float*)d_out, NPIX_BLKS, 1.f / (float)(B * HW));
}

// Round 7
// 198.430 us; speedup vs baseline: 4.8464x; 4.8464x over previous
//
#include <hip/hip_runtime.h>
#include <math.h>

constexpr int B = 2, H = 320, W = 512, D = 64;
constexpr int HW = H * W;
constexpr int R = 10;            // BLOCK // 2
constexpr int SEG = 80;          // output rows per cost block
constexpr int NSEG = H / SEG;    // 4
constexpr int RS = 548;          // vsbuf row stride (words)
constexpr float EPS = 1e-12f;

// Normalize + pack into float4 planes: nrm4[((t*B+b)*2+side)*HW + hw] = (c0,c1,c2,0)
__global__ void k_norm(const float* __restrict__ x, const float* __restrict__ gt,
                       float4* __restrict__ nrm4) {
    int idx = blockIdx.x * blockDim.x + threadIdx.x;
    if (idx >= 2 * B * HW) return;
    int t = idx / (B * HW);
    int rem = idx - t * (B * HW);
    int b = rem / HW;
    int hw = rem - b * HW;
    const float* p = (t == 0 ? x : gt) + (size_t)b * 6 * HW + hw;
    float v0 = p[0],      v1 = p[HW],     v2 = p[2 * HW];
    float v3 = p[3 * HW], v4 = p[4 * HW], v5 = p[5 * HW];
    float n1 = fmaxf(sqrtf(v0 * v0 + v1 * v1 + v2 * v2), EPS);
    float n2 = fmaxf(sqrtf(v3 * v3 + v4 * v4 + v5 * v5), EPS);
    float4* q = nrm4 + (size_t)(t * B + b) * 2 * HW + hw;
    q[0]  = make_float4(v0 / n1, v1 / n1, v2 / n1, 0.f);
    q[HW] = make_float4(v3 / n2, v4 / n2, v5 / n2, 0.f);
}

// 21x21 box-filtered SAD cost. Vertical rolling via a 24-slot REGISTER ring
// (delay 21: subtract slot (i+23)%24, write slot (i+20)%24 — static indices
// via full superstep unroll; a slot is subtracted 3 iterations before its
// overwrite). Horizontal rolling via LDS vs-row snapshots (round-4 scheme,
// one barrier per 8-row superstep, double-buffered parity).
// FUSE: additionally argmin 640 pixels of the COMPLETE cprev volume with
// independent loads interleaved per superstep (fills latency slack);
// ascending d + strict < == jnp.argmin tie semantics.
template<bool FUSE>
__global__ __launch_bounds__(512, 2) void k_cost(const float4* __restrict__ nrm4,
                                                 float* __restrict__ cost,
                                                 const float* __restrict__ cprev,
                                                 float* __restrict__ dprev, int t) {
    const int blk = blockIdx.x;
    const int combo = blk & 7;     // B*NSEG = 8 combos; pins (b,seg) to one XCD
    const int d = blk >> 3;
    const int b = combo >> 2;
    const int seg = combo & 3;
    const int w = threadIdx.x;
    const float4* L4 = nrm4 + (size_t)(t * B + b) * 2 * HW;
    const float4* R4 = L4 + HW;
    const bool val = (w >= d);
    const int wr = val ? (w - d) : 0;
    const int h0 = seg * SEG;

    __shared__ float vsb[2][8][RS];   // double-buffered vs snapshots (+10 halo each side)
    {   // zero halo pads of both parity buffers once
        int j = w >> 6, k = w & 63;
        if (k < 10)      { vsb[0][j][k] = 0.f;       vsb[1][j][k] = 0.f; }
        else if (k < 20) { vsb[0][j][512 + k] = 0.f; vsb[1][j][512 + k] = 0.f; }
    }

    auto diff = [&](int h) -> float {
        float4 l = L4[(size_t)h * W + w];
        float4 r = R4[(size_t)h * W + wr];
        float a = fabsf(l.x - r.x) + fabsf(l.y - r.y) + fabsf(l.z - r.z);
        float s = fabsf(l.x) + fabsf(l.y) + fabsf(l.z);  // r_shift == 0 when invalid
        return val ? a : s;
    };

    // Warm-up: rows [h0-10, h0+9] -> ring slots 0..19; slots 20..23 start 0.
    float ring[24];
    float vs = 0.f;
#pragma unroll
    for (int k = 0; k < 20; ++k) {
        int h = h0 - R + k;
        float dv = (h >= 0) ? diff(h) : 0.f;
        ring[k] = dv;
        vs += dv;
    }
    ring[20] = 0.f; ring[21] = 0.f; ring[22] = 0.f; ring[23] = 0.f;

    // fused-argmin state (pixels blk*640 .. blk*640+639)
    const float* cp0 = nullptr; const float* cp1 = nullptr;
    int px0 = 0, px1 = 0;
    float best0 = 3.4e38f, best1 = 3.4e38f;
    int bd0 = 0, bd1 = 0;
    if (FUSE) {
        px0 = blk * 640 + w;
        int b0 = (px0 >= HW) ? 1 : 0;
        cp0 = cprev + (size_t)b0 * D * HW + (px0 - b0 * HW);
        if (w < 128) {
            px1 = blk * 640 + 512 + w;
            int b1 = (px1 >= HW) ? 1 : 0;
            cp1 = cprev + (size_t)b1 * D * HW + (px1 - b1 * HW);
        }
    }

    const int cc = threadIdx.x >> 3;   // phase-2 col-run (0..63)
    const int jj = threadIdx.x & 7;    // phase-2 row slot (0..7)
    float* cp = cost + ((size_t)(b * D + d) * H) * W;

    int dc = 0;                        // fused d-counter (constant-folded by unroll)
#pragma unroll
    for (int ss = 0; ss < 10; ++ss) {
        const int nd = (ss < 4) ? 7 : 6;  // 4*7 + 6*6 = 64
        // phase 1: 8 new diffs (16 indep global loads), register-ring roll
        float dvv[8];
#pragma unroll
        for (int j = 0; j < 8; ++j) {
            int hn = h0 + ss * 8 + j + R;
            dvv[j] = (hn < H) ? diff(hn) : 0.f;
        }
        // fused argmin loads: independent, issued early
        float fv0[7], fv1[7];
        if (FUSE) {
#pragma unroll
            for (int q = 0; q < 7; ++q)
                if (q < nd) fv0[q] = cp0[(size_t)(dc + q) * HW];
            if (w < 128) {
#pragma unroll
                for (int q = 0; q < 7; ++q)
                    if (q < nd) fv1[q] = cp1[(size_t)(dc + q) * HW];
            }
        }
        float* vrow = &vsb[ss & 1][0][0];
#pragma unroll
        for (int j = 0; j < 8; ++j) {
            int i = ss * 8 + j;
            vs += dvv[j] - ring[(i + 23) % 24];   // subtract row i-21's diff (0 if outside)
            ring[(i + 20) % 24] = dvv[j];         // overwritten 3 iters after its subtract
            vrow[j * RS + 10 + w] = vs;
        }
        __syncthreads();
        // phase 2: 28-word window (7x b128) -> 8 horizontally-rolled outputs
        const float* vp = &vsb[ss & 1][jj][8 * cc];
        float wnd[28];
#pragma unroll
        for (int q = 0; q < 7; ++q) {
            float4 v4 = *(const float4*)(vp + 4 * q);
            wnd[4 * q] = v4.x; wnd[4 * q + 1] = v4.y;
            wnd[4 * q + 2] = v4.z; wnd[4 * q + 3] = v4.w;
        }
        float o = 0.f;
#pragma unroll
        for (int k = 0; k < 21; ++k) o += wnd[k];
        float out[8];
        out[0] = o;
#pragma unroll
        for (int k = 1; k < 8; ++k) { o += wnd[20 + k] - wnd[k - 1]; out[k] = o; }
        float* op = cp + (size_t)(h0 + ss * 8 + jj) * W + 8 * cc;
        *(float4*)(op)     = make_float4(out[0], out[1], out[2], out[3]);
        *(float4*)(op + 4) = make_float4(out[4], out[5], out[6], out[7]);
        // fused argmin consume (strict <, ascending d == jnp.argmin)
        if (FUSE) {
#pragma unroll
            for (int q = 0; q < 7; ++q)
                if (q < nd && fv0[q] < best0) { best0 = fv0[q]; bd0 = dc + q; }
            if (w < 128) {
#pragma unroll
                for (int q = 0; q < 7; ++q)
                    if (q < nd && fv1[q] < best1) { best1 = fv1[q]; bd1 = dc + q; }
            }
        }
        dc += nd;
    }
    if (FUSE) {
        dprev[px0] = (float)bd0;
        if (w < 128) dprev[px1] = (float)bd1;
    }
}

// Standalone argmin (fallback path only).
__global__ void k_argmin0(const float* __restrict__ cost, float* __restrict__ disp) {
    int idx = blockIdx.x * 256 + threadIdx.x;
    if (idx >= B * HW) return;
    int b = (idx >= HW) ? 1 : 0;
    const float* cp = cost + (size_t)b * D * HW + (idx - b * HW);
    float best = cp[0]; int bd = 0;
#pragma unroll 8
    for (int d = 1; d < D; ++d) {
        float v = cp[(size_t)d * HW];
        if (v < best) { best = v; bd = d; }
    }
    disp[idx] = (float)bd;
}

// argmin over costX + |argmin - disp0| + deterministic per-block partial sums.
__global__ void k_final(const float* __restrict__ cost1, const float* __restrict__ disp0,
                        float* __restrict__ part) {
    int idx = blockIdx.x * 256 + threadIdx.x;
    float s = 0.f;
    if (idx < B * HW) {
        int b = (idx >= HW) ? 1 : 0;
        const float* cp = cost1 + (size_t)b * D * HW + (idx - b * HW);
        float best = cp[0]; int bd = 0;
#pragma unroll 8
        for (int d = 1; d < D; ++d) {
            float v = cp[(size_t)d * HW];
            if (v < best) { best = v; bd = d; }
        }
        s = fabsf((float)bd - disp0[idx]);
    }
    __shared__ float sm[256];
    sm[threadIdx.x] = s;
    __syncthreads();
    for (int off = 128; off; off >>= 1) {
        if (threadIdx.x < off) sm[threadIdx.x] += sm[threadIdx.x + off];
        __syncthreads();
    }
    if (!threadIdx.x) part[blockIdx.x] = sm[0];
}

__global__ void k_red2(const float* __restrict__ part, float* __restrict__ out,
                       int nb, float inv) {
    __shared__ float sm[256];
    int tid = threadIdx.x;
    float s = 0.f;
    for (int i = tid; i < nb; i += 256) s += part[i];
    sm[tid] = s;
    __syncthreads();
    for (int off = 128; off; off >>= 1) {
        if (tid < off) sm[tid] += sm[tid + off];
        __syncthreads();
    }
    if (!tid) out[0] = sm[0] * inv;
}

extern "C" void kernel_launch(void* const* d_in, const int* in_sizes, int n_in,
                              void* d_out, int out_size, void* d_ws, size_t ws_size,
                              hipStream_t stream) {
    const float* x  = (const float*)d_in[0];
    const float* gt = (const float*)d_in[1];

    constexpr size_t NRM_F4 = (size_t)2 * B * 2 * HW;        // float4 count (21.0 MB)
    constexpr size_t COST_F = (size_t)B * D * HW;            // f32 count (83.9 MB)
    constexpr int NPIX_BLKS = (B * HW + 255) / 256;          // 1280
    constexpr int NRM_BLKS  = (2 * B * HW + 255) / 256;

    float4* nrm4 = (float4*)d_ws;
    float* cost0 = (float*)(nrm4 + NRM_F4);

    // Primary path needs two cost volumes (~190 MB); fallback (~106 MB) proven to fit.
    size_t need_primary = NRM_F4 * 16 + 2 * COST_F * 4 + (size_t)(B * HW + 4096) * 4;

    k_norm<<<NRM_BLKS, 256, 0, stream>>>(x, gt, nrm4);

    if (ws_size >= need_primary) {
        float* cost1 = cost0 + COST_F;
        float* disp0 = cost1 + COST_F;
        float* part  = disp0 + (size_t)B * HW;
        k_cost<false><<<B * NSEG * D, 512, 0, stream>>>(nrm4, cost0, nullptr, nullptr, 0);
        k_cost<true><<<B * NSEG * D, 512, 0, stream>>>(nrm4, cost1, cost0, disp0, 1);
        k_final<<<NPIX_BLKS, 256, 0, stream>>>(cost1, disp0, part);
        k_red2<<<1, 256, 0, stream>>>(part, (float*)d_out, NPIX_BLKS, 1.f / (float)(B * HW));
    } else {
        float* disp0 = cost0 + COST_F;
        float* part  = disp0 + (size_t)B * HW;
        k_cost<false><<<B * NSEG * D, 512, 0, stream>>>(nrm4, cost0, nullptr, nullptr, 0);
        k_argmin0<<<NPIX_BLKS, 256, 0, stream>>>(cost0, disp0);
        k_cost<false><<<B * NSEG * D, 512, 0, stream>>>(nrm4, cost0, nullptr, nullptr, 1);
        k_final<<<NPIX_BLKS, 256, 0, stream>>>(cost0, disp0, part);
        k_red2<<<1, 256, 0, stream>>>(part, (float*)d_out, NPIX_BLKS, 1.f / (float)(B * HW));
    }
}

// Round 8
// 193.585 us; speedup vs baseline: 4.9677x; 1.0250x over previous
//
#include <hip/hip_runtime.h>
#include <math.h>

constexpr int B = 2, H = 320, W = 512, D = 64;
constexpr int HW = H * W;
constexpr int R = 10;            // BLOCK // 2
constexpr int SEG = 80;          // output rows per cost block
constexpr int NSEG = H / SEG;    // 4
constexpr int RS = 548;          // vsbuf row stride (words)
constexpr float EPS = 1e-12f;

// Normalize + pack into float4 planes; float4-vectorized over 4 consecutive
// pixels (same per-pixel op sequence as scalar version -> bitwise identical).
__global__ void k_norm(const float* __restrict__ x, const float* __restrict__ gt,
                       float4* __restrict__ nrm4) {
    int idx = blockIdx.x * 256 + threadIdx.x;        // over 2*B*HW/4 pixel-quads
    if (idx >= 2 * B * (HW / 4)) return;
    int t = idx / (B * (HW / 4));
    int rem = idx - t * (B * (HW / 4));
    int b = rem / (HW / 4);
    int hw4 = rem - b * (HW / 4);
    const float* p = (t == 0 ? x : gt) + (size_t)b * 6 * HW + 4 * hw4;
    float4 c[6];
#pragma unroll
    for (int ch = 0; ch < 6; ++ch) c[ch] = *(const float4*)(p + (size_t)ch * HW);
    float4* q = nrm4 + (size_t)(t * B + b) * 2 * HW + 4 * hw4;
    float4 o0[4], o1[4];
    const float* cf = (const float*)c;
#pragma unroll
    for (int k = 0; k < 4; ++k) {
        float v0 = cf[k], v1 = cf[4 + k], v2 = cf[8 + k];
        float v3 = cf[12 + k], v4 = cf[16 + k], v5 = cf[20 + k];
        float n1 = fmaxf(sqrtf(v0 * v0 + v1 * v1 + v2 * v2), EPS);
        float n2 = fmaxf(sqrtf(v3 * v3 + v4 * v4 + v5 * v5), EPS);
        o0[k] = make_float4(v0 / n1, v1 / n1, v2 / n1, 0.f);
        o1[k] = make_float4(v3 / n2, v4 / n2, v5 / n2, 0.f);
    }
#pragma unroll
    for (int k = 0; k < 4; ++k) { q[k] = o0[k]; q[HW + k] = o1[k]; }
}

// 21x21 box-filtered SAD cost (round-4 structure: LDS diff ring + LDS vs
// snapshots, one barrier per 8-row superstep, double-buffered parity).
// FUSE: interleave argmin of the COMPLETE cprev volume (640 pixels/block,
// independent strided loads fill latency slack); ascending d + strict < ==
// jnp.argmin tie semantics (invalid-window costs are bitwise-equal across d).
template<bool FUSE>
__global__ __launch_bounds__(512, 2) void k_cost(const float4* __restrict__ nrm4,
                                                 float* __restrict__ cost,
                                                 const float* __restrict__ cprev,
                                                 float* __restrict__ dprev, int t) {
    const int blk = blockIdx.x;
    const int combo = blk & 7;     // B*NSEG = 8 combos; pins (b,seg) to one XCD
    const int d = blk >> 3;
    const int b = combo >> 2;
    const int seg = combo & 3;
    const int w = threadIdx.x;
    const float4* L4 = nrm4 + (size_t)(t * B + b) * 2 * HW;
    const float4* R4 = L4 + HW;
    const bool val = (w >= d);
    const int wr = val ? (w - d) : 0;
    const int h0 = seg * SEG;

    __shared__ float ring[21][W];     // diff delay line, strictly per-column
    __shared__ float vsb[2][8][RS];   // double-buffered vs snapshots (+10 halo each side)
    {   // zero halo pads of both parity buffers once
        int j = w >> 6, k = w & 63;
        if (k < 10)      { vsb[0][j][k] = 0.f;       vsb[1][j][k] = 0.f; }
        else if (k < 20) { vsb[0][j][512 + k] = 0.f; vsb[1][j][512 + k] = 0.f; }
    }

    auto diff = [&](int h) -> float {
        float4 l = L4[(size_t)h * W + w];
        if (val) {
            float4 r = R4[(size_t)h * W + wr];
            return fabsf(l.x - r.x) + fabsf(l.y - r.y) + fabsf(l.z - r.z);
        }
        return fabsf(l.x) + fabsf(l.y) + fabsf(l.z);  // r_shift == 0 when invalid
    };

    // Warm-up: rows [h0-10, h0+9] -> ring slots 0..19; slot 20 = row h0-11 (zero).
    float vs = 0.f;
    for (int k = 0; k < 20; ++k) {
        int h = h0 - R + k;
        float dv0 = (h >= 0) ? diff(h) : 0.f;
        ring[k][w] = dv0;
        vs += dv0;
    }
    ring[20][w] = 0.f;

    // fused-argmin state (pixels blk*640 .. blk*640+639)
    const float* cp0 = nullptr; const float* cp1 = nullptr;
    int px0 = 0, px1 = 0;
    float best0 = 3.4e38f, best1 = 3.4e38f;
    int bd0 = 0, bd1 = 0;
    if (FUSE) {
        px0 = blk * 640 + w;
        int b0 = (px0 >= HW) ? 1 : 0;
        cp0 = cprev + (size_t)b0 * D * HW + (px0 - b0 * HW);
        if (w < 128) {
            px1 = blk * 640 + 512 + w;
            int b1 = (px1 >= HW) ? 1 : 0;
            cp1 = cprev + (size_t)b1 * D * HW + (px1 - b1 * HW);
        }
    }

    const int cc = threadIdx.x >> 3;   // phase-2 col-run (0..63)
    const int jj = threadIdx.x & 7;    // phase-2 row slot (0..7)
    float* cp = cost + ((size_t)(b * D + d) * H) * W;

    int slot0 = 20;
    int dc = 0;
    for (int ss = 0; ss < 10; ++ss) {
        const int nd = (ss < 4) ? 7 : 6;  // 4*7 + 6*6 = 64 fused d's
        int sl[8];
        float dold[8], dv[8];
#pragma unroll
        for (int j = 0; j < 8; ++j) { int s2 = slot0 + j; if (s2 >= 21) s2 -= 21; sl[j] = s2; }
#pragma unroll
        for (int j = 0; j < 8; ++j) dold[j] = ring[sl[j]][w];     // 8 indep LDS reads
#pragma unroll
        for (int j = 0; j < 8; ++j) {                             // 16 indep global loads
            int hn = h0 + ss * 8 + j + R;
            dv[j] = (hn < H) ? diff(hn) : 0.f;
        }
        float fv0[7], fv1[7];
        if (FUSE) {                                               // indep strided loads
#pragma unroll
            for (int q = 0; q < 7; ++q)
                if (q < nd) fv0[q] = cp0[(size_t)(dc + q) * HW];
            if (w < 128) {
#pragma unroll
                for (int q = 0; q < 7; ++q)
                    if (q < nd) fv1[q] = cp1[(size_t)(dc + q) * HW];
            }
        }
#pragma unroll
        for (int j = 0; j < 8; ++j) ring[sl[j]][w] = dv[j];       // writes after all reads
        float* vrow = &vsb[ss & 1][0][0];
#pragma unroll
        for (int j = 0; j < 8; ++j) { vs += dv[j] - dold[j]; vrow[j * RS + 10 + w] = vs; }
        __syncthreads();
        // phase 2: 28-word window (7x b128) -> 8 horizontally-rolled outputs
        const float* vp = &vsb[ss & 1][jj][8 * cc];
        float wnd[28];
#pragma unroll
        for (int q = 0; q < 7; ++q) {
            float4 v4 = *(const float4*)(vp + 4 * q);
            wnd[4 * q] = v4.x; wnd[4 * q + 1] = v4.y;
            wnd[4 * q + 2] = v4.z; wnd[4 * q + 3] = v4.w;
        }
        float o = 0.f;
#pragma unroll
        for (int k = 0; k < 21; ++k) o += wnd[k];
        float out[8];
        out[0] = o;
#pragma unroll
        for (int k = 1; k < 8; ++k) { o += wnd[20 + k] - wnd[k - 1]; out[k] = o; }
        float* op = cp + (size_t)(h0 + ss * 8 + jj) * W + 8 * cc;
        *(float4*)(op)     = make_float4(out[0], out[1], out[2], out[3]);
        *(float4*)(op + 4) = make_float4(out[4], out[5], out[6], out[7]);
        if (FUSE) {                    // consume fused loads (strict <, ascending d)
#pragma unroll
            for (int q = 0; q < 7; ++q)
                if (q < nd && fv0[q] < best0) { best0 = fv0[q]; bd0 = dc + q; }
            if (w < 128) {
#pragma unroll
                for (int q = 0; q < 7; ++q)
                    if (q < nd && fv1[q] < best1) { best1 = fv1[q]; bd1 = dc + q; }
            }
        }
        dc += nd;
        slot0 += 8; if (slot0 >= 21) slot0 -= 21;
    }
    if (FUSE) {
        dprev[px0] = (float)bd0;
        if (w < 128) dprev[px1] = (float)bd1;
    }
}

// Scan-order argmin: thread exclusively owns 4 consecutive pixels, reads one
// coalesced float4 per d (state in registers, no atomics). Strict < ascending
// d == jnp.argmin. Blocks never straddle batch boundary (HW % 1024 == 0).
__global__ void k_amin(const float* __restrict__ cost, float* __restrict__ disp) {
    int blk = blockIdx.x;                 // 320 blocks x 256 thr x 4 px = B*HW
    int b = (blk * 1024 >= HW) ? 1 : 0;
    int hw0 = blk * 1024 - b * HW + threadIdx.x * 4;
    const float* cp = cost + (size_t)b * D * HW + hw0;
    float4 v = *(const float4*)cp;
    float bb[4] = {v.x, v.y, v.z, v.w};
    int bd[4] = {0, 0, 0, 0};
    for (int d = 1; d < D; ++d) {
        v = *(const float4*)(cp + (size_t)d * HW);
        if (v.x < bb[0]) { bb[0] = v.x; bd[0] = d; }
        if (v.y < bb[1]) { bb[1] = v.y; bd[1] = d; }
        if (v.z < bb[2]) { bb[2] = v.z; bd[2] = d; }
        if (v.w < bb[3]) { bb[3] = v.w; bd[3] = d; }
    }
    *(float4*)(disp + (size_t)blk * 1024 + threadIdx.x * 4) =
        make_float4((float)bd[0], (float)bd[1], (float)bd[2], (float)bd[3]);
}

// Scan-order argmin over cost1 + |argmin - disp0| + deterministic partials.
__global__ void k_fin(const float* __restrict__ cost1, const float* __restrict__ disp0,
                      float* __restrict__ part) {
    int blk = blockIdx.x;
    int b = (blk * 1024 >= HW) ? 1 : 0;
    int hw0 = blk * 1024 - b * HW + threadIdx.x * 4;
    const float* cp = cost1 + (size_t)b * D * HW + hw0;
    float4 v = *(const float4*)cp;
    float bb[4] = {v.x, v.y, v.z, v.w};
    int bd[4] = {0, 0, 0, 0};
    for (int d = 1; d < D; ++d) {
        v = *(const float4*)(cp + (size_t)d * HW);
        if (v.x < bb[0]) { bb[0] = v.x; bd[0] = d; }
        if (v.y < bb[1]) { bb[1] = v.y; bd[1] = d; }
        if (v.z < bb[2]) { bb[2] = v.z; bd[2] = d; }
        if (v.w < bb[3]) { bb[3] = v.w; bd[3] = d; }
    }
    float4 d0 = *(const float4*)(disp0 + (size_t)blk * 1024 + threadIdx.x * 4);
    float s = fabsf((float)bd[0] - d0.x) + fabsf((float)bd[1] - d0.y) +
              fabsf((float)bd[2] - d0.z) + fabsf((float)bd[3] - d0.w);
    __shared__ float sm[256];
    sm[threadIdx.x] = s;
    __syncthreads();
    for (int off = 128; off; off >>= 1) {
        if (threadIdx.x < off) sm[threadIdx.x] += sm[threadIdx.x + off];
        __syncthreads();
    }
    if (!threadIdx.x) part[blockIdx.x] = sm[0];
}

__global__ void k_red2(const float* __restrict__ part, float* __restrict__ out,
                       int nb, float inv) {
    __shared__ float sm[256];
    int tid = threadIdx.x;
    float s = 0.f;
    for (int i = tid; i < nb; i += 256) s += part[i];
    sm[tid] = s;
    __syncthreads();
    for (int off = 128; off; off >>= 1) {
        if (tid < off) sm[tid] += sm[tid + off];
        __syncthreads();
    }
    if (!tid) out[0] = sm[0] * inv;
}

extern "C" void kernel_launch(void* const* d_in, const int* in_sizes, int n_in,
                              void* d_out, int out_size, void* d_ws, size_t ws_size,
                              hipStream_t stream) {
    const float* x  = (const float*)d_in[0];
    const float* gt = (const float*)d_in[1];

    constexpr size_t NRM_F4 = (size_t)2 * B * 2 * HW;        // float4 count (21.0 MB)
    constexpr size_t COST_F = (size_t)B * D * HW;            // f32 count (83.9 MB)
    constexpr int AMIN_BLKS = B * HW / 1024;                 // 320
    constexpr int NRM_BLKS  = (2 * B * (HW / 4) + 255) / 256;

    float4* nrm4 = (float4*)d_ws;
    float* cost0 = (float*)(nrm4 + NRM_F4);

    size_t need_primary = NRM_F4 * 16 + 2 * COST_F * 4 + (size_t)(B * HW + 4096) * 4;

    k_norm<<<NRM_BLKS, 256, 0, stream>>>(x, gt, nrm4);

    if (ws_size >= need_primary) {
        float* cost1 = cost0 + COST_F;
        float* disp0 = cost1 + COST_F;
        float* part  = disp0 + (size_t)B * HW;
        k_cost<false><<<B * NSEG * D, 512, 0, stream>>>(nrm4, cost0, nullptr, nullptr, 0);
        k_cost<true><<<B * NSEG * D, 512, 0, stream>>>(nrm4, cost1, cost0, disp0, 1);
        k_fin<<<AMIN_BLKS, 256, 0, stream>>>(cost1, disp0, part);
        k_red2<<<1, 256, 0, stream>>>(part, (float*)d_out, AMIN_BLKS, 1.f / (float)(B * HW));
    } else {
        float* disp0 = cost0 + COST_F;
        float* part  = disp0 + (size_t)B * HW;
        k_cost<false><<<B * NSEG * D, 512, 0, stream>>>(nrm4, cost0, nullptr, nullptr, 0);
        k_amin<<<AMIN_BLKS, 256, 0, stream>>>(cost0, disp0);
        k_cost<false><<<B * NSEG * D, 512, 0, stream>>>(nrm4, cost0, nullptr, nullptr, 1);
        k_fin<<<AMIN_BLKS, 256, 0, stream>>>(cost0, disp0, part);
        k_red2<<<1, 256, 0, stream>>>(part, (float*)d_out, AMIN_BLKS, 1.f / (float)(B * HW));
    }
}